// Round 6
// baseline (186.248 us; speedup 1.0000x reference)
//
#include <hip/hip_runtime.h>

// Loss_8615704396494: masked L1 + 0.1 * bone-direction MSE over [B=128,T=1024,150] fp32.
// R5 post-mortem: L3-warm dispatches still took 63 us -> NOT HBM-bound; the LDS data
// round-trip (scalar ds_read_b32 of 12-byte joints) + barrier lockstep was the floor.
// R6: wave-per-row, no LDS data path at all.
//   lane l (<50) owns joint l: loads 12 B float3 from preds & targets (wave reads a
//   dense 600 B row -> coalesced), neighbor joint (l+1)%50 via 6 __shfl (bpermute),
//   bone l computed fully in-lane. No __syncthreads in the main loop. One-row
//   register prefetch; 32 waves/CU provide cross-wave latency hiding.

#define ROW_F    150
#define N_JOINTS 50
#define GRID     2048          // 8 blocks/CU target, 8192 waves, 16 rows/wave

__global__ __launch_bounds__(256, 8) void loss_kernel(
    const float* __restrict__ preds,
    const float* __restrict__ targets,
    float* __restrict__ out,
    int n_rows, float inv_count)
{
    const float EPS = 1e-8f;
    const int tid  = threadIdx.x;
    const int lane = tid & 63;
    const int wid  = tid >> 6;

    const int gwave = blockIdx.x * 4 + wid;    // global wave id
    const int nwave = GRID * 4;                // 8192

    const bool valid = (lane < N_JOINTS);
    const int  off   = valid ? 3 * lane : 0;   // invalid lanes read row start (zeroed later)
    const int  nsrc  = (lane >= N_JOINTS - 1) ? 0 : lane + 1;   // neighbor lane (49->0)

    float l1 = 0.0f, mse = 0.0f;

    int r = gwave;                             // n_rows = 131072 > nwave, so r valid
    float3 cp = *reinterpret_cast<const float3*>(preds   + (size_t)r * ROW_F + off);
    float3 ct = *reinterpret_cast<const float3*>(targets + (size_t)r * ROW_F + off);

    while (true) {
        // ---- prefetch next row (clamped; extra tail load is L1-resident) ----
        int rn = r + nwave;
        int rc = (rn < n_rows) ? rn : (n_rows - 1);
        float3 np = *reinterpret_cast<const float3*>(preds   + (size_t)rc * ROW_F + off);
        float3 nt = *reinterpret_cast<const float3*>(targets + (size_t)rc * ROW_F + off);

        // ---- compute current row ----
        // zero invalid lanes' targets => all their downstream contributions vanish
        float t0 = valid ? ct.x : 0.0f;
        float t1 = valid ? ct.y : 0.0f;
        float t2 = valid ? ct.z : 0.0f;
        // masked pred: pm = (t != 0) ? p : 0   (masked target == target)
        float pm0 = (t0 != 0.0f) ? cp.x : 0.0f;
        float pm1 = (t1 != 0.0f) ? cp.y : 0.0f;
        float pm2 = (t2 != 0.0f) ? cp.z : 0.0f;

        l1 += fabsf(pm0 - t0) + fabsf(pm1 - t1) + fabsf(pm2 - t2);

        // neighbor joint (dst of bone l): shuffle masked pred + target
        float qm0 = __shfl(pm0, nsrc, 64);
        float qm1 = __shfl(pm1, nsrc, 64);
        float qm2 = __shfl(pm2, nsrc, 64);
        float u0  = __shfl(t0,  nsrc, 64);
        float u1  = __shfl(t1,  nsrc, 64);
        float u2  = __shfl(t2,  nsrc, 64);

        float dp0 = pm0 - qm0, dp1 = pm1 - qm1, dp2 = pm2 - qm2;
        float dt0 = t0  - u0,  dt1 = t1  - u1,  dt2 = t2  - u2;
        float lp = dp0 * dp0 + dp1 * dp1 + dp2 * dp2;
        float lt = dt0 * dt0 + dt1 * dt1 + dt2 * dt2;
        float ip = __builtin_amdgcn_rcpf(__builtin_amdgcn_sqrtf(lp) + EPS);
        float iq = __builtin_amdgcn_rcpf(__builtin_amdgcn_sqrtf(lt) + EPS);

        // direction diff, masked by SOURCE joint's mask (t_c != 0)
        float d0 = dp0 * ip - dt0 * iq;  d0 = (t0 != 0.0f) ? d0 : 0.0f;
        float d1 = dp1 * ip - dt1 * iq;  d1 = (t1 != 0.0f) ? d1 : 0.0f;
        float d2 = dp2 * ip - dt2 * iq;  d2 = (t2 != 0.0f) ? d2 : 0.0f;
        mse += d0 * d0 + d1 * d1 + d2 * d2;

        if (rn >= n_rows) break;
        cp = np; ct = nt; r = rn;
    }

    // ---- Reduce: loss = (l1 + 0.1*mse) / COUNT ----
    float part = (l1 + 0.1f * mse) * inv_count;
#pragma unroll
    for (int o = 32; o > 0; o >>= 1)
        part += __shfl_down(part, o, 64);

    __shared__ float wsum[4];
    if (lane == 0) wsum[wid] = part;
    __syncthreads();
    if (tid == 0) {
        float s = wsum[0] + wsum[1] + wsum[2] + wsum[3];
        atomicAdd(out, s);
    }
}

extern "C" void kernel_launch(void* const* d_in, const int* in_sizes, int n_in,
                              void* d_out, int out_size, void* d_ws, size_t ws_size,
                              hipStream_t stream)
{
    const float* preds   = (const float*)d_in[0];
    const float* targets = (const float*)d_in[1];
    float* out = (float*)d_out;

    // d_out is re-poisoned to 0xAA before every timed launch — zero it (capture-safe).
    hipMemsetAsync(out, 0, sizeof(float) * out_size, stream);

    int n_elems = in_sizes[0];              // 128*1024*150 = 19,660,800
    int n_rows  = n_elems / ROW_F;          // 131072
    float inv_count = 1.0f / (float)n_elems;

    loss_kernel<<<GRID, 256, 0, stream>>>(preds, targets, out, n_rows, inv_count);
}

// Round 7
// 185.539 us; speedup vs baseline: 1.0038x; 1.0038x over previous
//
#include <hip/hip_runtime.h>

// Loss_8615704396494: masked L1 + 0.1 * bone-direction MSE over [B=128,T=1024,150] fp32.
// R6 post-mortem: all structures plateau 63-71 us; L3-warm runs equally slow; occupancy
// 66%, VALU 17%, HBM 1.15 TB/s -> latency-bound on per-wave MLP (1 row = 2 VMEM in
// flight per wave). R7: depth-4 register software pipeline on the wave-per-row kernel.
// 4 named row-slots; compute oldest while 3 rows (6 VMEM) stay in flight; no barriers,
// so the compiler can emit fine-grained vmcnt(N) waits. ~50 VGPR -> 8 waves/SIMD kept.

#define ROW_F    150
#define N_JOINTS 50
#define GRID     2048                  // 8 blocks/CU, 8192 waves
#define NWAVE    (GRID * 4)

__device__ __forceinline__ void row_compute(float3 cp, float3 ct, bool valid, int nsrc,
                                            float& l1, float& mse)
{
    const float EPS = 1e-8f;
    // zero invalid lanes' targets => all their downstream contributions vanish
    float t0 = valid ? ct.x : 0.0f;
    float t1 = valid ? ct.y : 0.0f;
    float t2 = valid ? ct.z : 0.0f;
    // masked pred: pm = (t != 0) ? p : 0   (masked target == target)
    float pm0 = (t0 != 0.0f) ? cp.x : 0.0f;
    float pm1 = (t1 != 0.0f) ? cp.y : 0.0f;
    float pm2 = (t2 != 0.0f) ? cp.z : 0.0f;

    l1 += fabsf(pm0 - t0) + fabsf(pm1 - t1) + fabsf(pm2 - t2);

    // neighbor joint (dst of bone `lane`): shuffle masked pred + target
    float qm0 = __shfl(pm0, nsrc, 64);
    float qm1 = __shfl(pm1, nsrc, 64);
    float qm2 = __shfl(pm2, nsrc, 64);
    float u0  = __shfl(t0,  nsrc, 64);
    float u1  = __shfl(t1,  nsrc, 64);
    float u2  = __shfl(t2,  nsrc, 64);

    float dp0 = pm0 - qm0, dp1 = pm1 - qm1, dp2 = pm2 - qm2;
    float dt0 = t0  - u0,  dt1 = t1  - u1,  dt2 = t2  - u2;
    float lp = dp0 * dp0 + dp1 * dp1 + dp2 * dp2;
    float lt = dt0 * dt0 + dt1 * dt1 + dt2 * dt2;
    float ip = __builtin_amdgcn_rcpf(__builtin_amdgcn_sqrtf(lp) + EPS);
    float iq = __builtin_amdgcn_rcpf(__builtin_amdgcn_sqrtf(lt) + EPS);

    // direction diff, masked by SOURCE joint's mask (t_c != 0)
    float d0 = dp0 * ip - dt0 * iq;  d0 = (t0 != 0.0f) ? d0 : 0.0f;
    float d1 = dp1 * ip - dt1 * iq;  d1 = (t1 != 0.0f) ? d1 : 0.0f;
    float d2 = dp2 * ip - dt2 * iq;  d2 = (t2 != 0.0f) ? d2 : 0.0f;
    mse += d0 * d0 + d1 * d1 + d2 * d2;
}

__global__ __launch_bounds__(256, 8) void loss_kernel(
    const float* __restrict__ preds,
    const float* __restrict__ targets,
    float* __restrict__ out,
    int n_rows, float inv_count)
{
    const int tid  = threadIdx.x;
    const int lane = tid & 63;
    const int wid  = tid >> 6;
    const int gwave = blockIdx.x * 4 + wid;

    const bool valid = (lane < N_JOINTS);
    const int  off   = valid ? 3 * lane : 0;
    const int  nsrc  = (lane >= N_JOINTS - 1) ? 0 : lane + 1;   // neighbor lane (49->0)

    // per-lane byte pointers; pipeline stage stride = NWAVE rows
    const char* pb = (const char*)preds   + (((size_t)gwave * ROW_F + off) << 2);
    const char* tb = (const char*)targets + (((size_t)gwave * ROW_F + off) << 2);
    const size_t step = (size_t)NWAVE * ROW_F * 4;   // 4,915,200 B

    const int iters = n_rows / NWAVE;                // 16 (divisible by 4)

    float l1 = 0.0f, mse = 0.0f;

    // ---- prologue: fill 4 slots ----
    float3 pA = *(const float3*)(pb + 0 * step);  float3 tA = *(const float3*)(tb + 0 * step);
    float3 pB = *(const float3*)(pb + 1 * step);  float3 tB = *(const float3*)(tb + 1 * step);
    float3 pC = *(const float3*)(pb + 2 * step);  float3 tC = *(const float3*)(tb + 2 * step);
    float3 pD = *(const float3*)(pb + 3 * step);  float3 tD = *(const float3*)(tb + 3 * step);

    const char* pn = pb + 4 * step;
    const char* tn = tb + 4 * step;

    // ---- main: compute oldest slot, reissue its load 4 stages ahead ----
    for (int i = 4; i < iters; i += 4) {
        row_compute(pA, tA, valid, nsrc, l1, mse);
        pA = *(const float3*)(pn + 0 * step);  tA = *(const float3*)(tn + 0 * step);
        row_compute(pB, tB, valid, nsrc, l1, mse);
        pB = *(const float3*)(pn + 1 * step);  tB = *(const float3*)(tn + 1 * step);
        row_compute(pC, tC, valid, nsrc, l1, mse);
        pC = *(const float3*)(pn + 2 * step);  tC = *(const float3*)(tn + 2 * step);
        row_compute(pD, tD, valid, nsrc, l1, mse);
        pD = *(const float3*)(pn + 3 * step);  tD = *(const float3*)(tn + 3 * step);
        pn += 4 * step;  tn += 4 * step;
    }

    // ---- epilogue: drain the 4 slots ----
    row_compute(pA, tA, valid, nsrc, l1, mse);
    row_compute(pB, tB, valid, nsrc, l1, mse);
    row_compute(pC, tC, valid, nsrc, l1, mse);
    row_compute(pD, tD, valid, nsrc, l1, mse);

    // ---- Reduce: loss = (l1 + 0.1*mse) / COUNT ----
    float part = (l1 + 0.1f * mse) * inv_count;
#pragma unroll
    for (int o = 32; o > 0; o >>= 1)
        part += __shfl_down(part, o, 64);

    __shared__ float wsum[4];
    if (lane == 0) wsum[wid] = part;
    __syncthreads();
    if (tid == 0) {
        float s = wsum[0] + wsum[1] + wsum[2] + wsum[3];
        atomicAdd(out, s);
    }
}

extern "C" void kernel_launch(void* const* d_in, const int* in_sizes, int n_in,
                              void* d_out, int out_size, void* d_ws, size_t ws_size,
                              hipStream_t stream)
{
    const float* preds   = (const float*)d_in[0];
    const float* targets = (const float*)d_in[1];
    float* out = (float*)d_out;

    // d_out is re-poisoned to 0xAA before every timed launch — zero it (capture-safe).
    hipMemsetAsync(out, 0, sizeof(float) * out_size, stream);

    int n_elems = in_sizes[0];              // 128*1024*150 = 19,660,800
    int n_rows  = n_elems / ROW_F;          // 131072 = 8192 waves * 16 rows
    float inv_count = 1.0f / (float)n_elems;

    loss_kernel<<<GRID, 256, 0, stream>>>(preds, targets, out, n_rows, inv_count);
}

// Round 8
// 177.071 us; speedup vs baseline: 1.0518x; 1.0478x over previous
//
#include <hip/hip_runtime.h>

// Loss_8615704396494: masked L1 + 0.1 * bone-direction MSE over [B=128,T=1024,150] fp32.
// R7 post-mortem: depth-4 register pipeline spilled to scratch (launch_bounds(256,8)
// = 64-VGPR cap; WRITE_SIZE 8.26 MB = 16 B/thread of spill) -> pipeline defeated.
// R1 evidence: deep per-thread MLP alone sustained 2.7 TB/s with 8 waves/CU.
// R8: same wave-per-row + depth-4 pipeline, launch_bounds(256,4) = 128 VGPR budget
// (pipeline needs ~60, no spill), GRID=1024 (16 waves/CU), 32 rows/wave.
// Steady state: 8 outstanding VMEM/wave x 16 waves/CU = 128 in flight per CU.

#define ROW_F    150
#define N_JOINTS 50
#define GRID     1024                  // 4 blocks/CU, 4096 waves
#define NWAVE    (GRID * 4)

__device__ __forceinline__ void row_compute(float3 cp, float3 ct, bool valid, int nsrc,
                                            float& l1, float& mse)
{
    const float EPS = 1e-8f;
    // zero invalid lanes' targets => all their downstream contributions vanish
    float t0 = valid ? ct.x : 0.0f;
    float t1 = valid ? ct.y : 0.0f;
    float t2 = valid ? ct.z : 0.0f;
    // masked pred: pm = (t != 0) ? p : 0   (masked target == target)
    float pm0 = (t0 != 0.0f) ? cp.x : 0.0f;
    float pm1 = (t1 != 0.0f) ? cp.y : 0.0f;
    float pm2 = (t2 != 0.0f) ? cp.z : 0.0f;

    l1 += fabsf(pm0 - t0) + fabsf(pm1 - t1) + fabsf(pm2 - t2);

    // neighbor joint (dst of bone `lane`): shuffle masked pred + target
    float qm0 = __shfl(pm0, nsrc, 64);
    float qm1 = __shfl(pm1, nsrc, 64);
    float qm2 = __shfl(pm2, nsrc, 64);
    float u0  = __shfl(t0,  nsrc, 64);
    float u1  = __shfl(t1,  nsrc, 64);
    float u2  = __shfl(t2,  nsrc, 64);

    float dp0 = pm0 - qm0, dp1 = pm1 - qm1, dp2 = pm2 - qm2;
    float dt0 = t0  - u0,  dt1 = t1  - u1,  dt2 = t2  - u2;
    float lp = dp0 * dp0 + dp1 * dp1 + dp2 * dp2;
    float lt = dt0 * dt0 + dt1 * dt1 + dt2 * dt2;
    float ip = __builtin_amdgcn_rcpf(__builtin_amdgcn_sqrtf(lp) + EPS);
    float iq = __builtin_amdgcn_rcpf(__builtin_amdgcn_sqrtf(lt) + EPS);

    // direction diff, masked by SOURCE joint's mask (t_c != 0)
    float d0 = dp0 * ip - dt0 * iq;  d0 = (t0 != 0.0f) ? d0 : 0.0f;
    float d1 = dp1 * ip - dt1 * iq;  d1 = (t1 != 0.0f) ? d1 : 0.0f;
    float d2 = dp2 * ip - dt2 * iq;  d2 = (t2 != 0.0f) ? d2 : 0.0f;
    mse += d0 * d0 + d1 * d1 + d2 * d2;
}

__global__ __launch_bounds__(256, 4) void loss_kernel(
    const float* __restrict__ preds,
    const float* __restrict__ targets,
    float* __restrict__ out,
    int n_rows, float inv_count)
{
    const int tid  = threadIdx.x;
    const int lane = tid & 63;
    const int wid  = tid >> 6;
    const int gwave = blockIdx.x * 4 + wid;

    const bool valid = (lane < N_JOINTS);
    const int  off   = valid ? 3 * lane : 0;
    const int  nsrc  = (lane >= N_JOINTS - 1) ? 0 : lane + 1;   // neighbor lane (49->0)

    // per-lane byte pointers; pipeline stage stride = NWAVE rows
    const char* pb = (const char*)preds   + (((size_t)gwave * ROW_F + off) << 2);
    const char* tb = (const char*)targets + (((size_t)gwave * ROW_F + off) << 2);
    const size_t step = (size_t)NWAVE * ROW_F * 4;   // bytes between pipeline stages

    const int iters = n_rows / NWAVE;                // 32 (divisible by 4)

    float l1 = 0.0f, mse = 0.0f;

    // ---- prologue: fill 4 slots (8 VMEM in flight) ----
    float3 pA = *(const float3*)(pb + 0 * step);  float3 tA = *(const float3*)(tb + 0 * step);
    float3 pB = *(const float3*)(pb + 1 * step);  float3 tB = *(const float3*)(tb + 1 * step);
    float3 pC = *(const float3*)(pb + 2 * step);  float3 tC = *(const float3*)(tb + 2 * step);
    float3 pD = *(const float3*)(pb + 3 * step);  float3 tD = *(const float3*)(tb + 3 * step);

    const char* pn = pb + 4 * step;
    const char* tn = tb + 4 * step;

    // ---- main: compute oldest slot, reissue its load 4 stages ahead ----
    for (int i = 4; i < iters; i += 4) {
        row_compute(pA, tA, valid, nsrc, l1, mse);
        pA = *(const float3*)(pn + 0 * step);  tA = *(const float3*)(tn + 0 * step);
        row_compute(pB, tB, valid, nsrc, l1, mse);
        pB = *(const float3*)(pn + 1 * step);  tB = *(const float3*)(tn + 1 * step);
        row_compute(pC, tC, valid, nsrc, l1, mse);
        pC = *(const float3*)(pn + 2 * step);  tC = *(const float3*)(tn + 2 * step);
        row_compute(pD, tD, valid, nsrc, l1, mse);
        pD = *(const float3*)(pn + 3 * step);  tD = *(const float3*)(tn + 3 * step);
        pn += 4 * step;  tn += 4 * step;
    }

    // ---- epilogue: drain the 4 slots ----
    row_compute(pA, tA, valid, nsrc, l1, mse);
    row_compute(pB, tB, valid, nsrc, l1, mse);
    row_compute(pC, tC, valid, nsrc, l1, mse);
    row_compute(pD, tD, valid, nsrc, l1, mse);

    // ---- Reduce: loss = (l1 + 0.1*mse) / COUNT ----
    float part = (l1 + 0.1f * mse) * inv_count;
#pragma unroll
    for (int o = 32; o > 0; o >>= 1)
        part += __shfl_down(part, o, 64);

    __shared__ float wsum[4];
    if (lane == 0) wsum[wid] = part;
    __syncthreads();
    if (tid == 0) {
        float s = wsum[0] + wsum[1] + wsum[2] + wsum[3];
        atomicAdd(out, s);
    }
}

extern "C" void kernel_launch(void* const* d_in, const int* in_sizes, int n_in,
                              void* d_out, int out_size, void* d_ws, size_t ws_size,
                              hipStream_t stream)
{
    const float* preds   = (const float*)d_in[0];
    const float* targets = (const float*)d_in[1];
    float* out = (float*)d_out;

    // d_out is re-poisoned to 0xAA before every timed launch — zero it (capture-safe).
    hipMemsetAsync(out, 0, sizeof(float) * out_size, stream);

    int n_elems = in_sizes[0];              // 128*1024*150 = 19,660,800
    int n_rows  = n_elems / ROW_F;          // 131072 = 4096 waves * 32 rows
    float inv_count = 1.0f / (float)n_elems;

    loss_kernel<<<GRID, 256, 0, stream>>>(preds, targets, out, n_rows, inv_count);
}